// Round 12
// baseline (2700.380 us; speedup 1.0000x reference)
//
#include <hip/hip_runtime.h>
#include <math.h>

typedef unsigned short ushort_t;
typedef __attribute__((ext_vector_type(8))) short bf16x8;
typedef __attribute__((ext_vector_type(4))) float f32x4;
typedef __attribute__((ext_vector_type(4))) unsigned short us4;
typedef __attribute__((ext_vector_type(8))) unsigned short us8;

#define NBATCH 2
#define TT 4
#define DD 768
#define DI_ 1536
#define NS_ 16
#define RK_ 48
#define KC_ 4
#define DEPTH_ 16
#define NRUN 15             // layer 16's compute is dead (only res += h survives)
#define LV 448
#define NROWS (NBATCH*LV)   // 896
#define NCH 14              // scan chunks
#define NCHA 13             // chunks computed by pass A
#define CLEN 32             // chunk length (14*32 = 448)

// bf16 weight arena (ushorts): WIN[15*2359296] | WOUT[15*1179648] | WX[15*2*196608]
#define WIN_SZ   (NRUN*2359296)
#define WOUT_SZ  (NRUN*1179648)
#define WX_SZ    (NRUN*2*196608)
#define WALL_USH (WIN_SZ + WOUT_SZ + WX_SZ)

#define ABUF 2048   // 64*32 ushorts per A buffer
#define BBUF 4096   // 128*32 ushorts per B buffer

// castall unit counts (8 ushorts per unit)
#define U_WIN  (WIN_SZ/8)
#define U_WOUT (WOUT_SZ/8)
#define U_WX   (WX_SZ/8)
#define U_WPV  (589824/8)
#define U_WPA  (196608/8)
#define U_ALL  (U_WIN+U_WOUT+U_WX+U_WPV+U_WPA)

__device__ __forceinline__ float silu_f(float x) { return x / (1.f + __expf(-x)); }
__device__ __forceinline__ ushort_t f2bf(float x) {
  unsigned int u = __float_as_uint(x);
  return (ushort_t)((u + 0x7FFFu + ((u >> 16) & 1u)) >> 16);
}
__device__ __forceinline__ float bf2f(ushort_t h) {
  return __uint_as_float(((unsigned int)h) << 16);
}

typedef const __attribute__((address_space(1))) unsigned int* gas1_t;
typedef __attribute__((address_space(3))) unsigned int* las3_t;
__device__ __forceinline__ void gll16(const ushort_t* g, ushort_t* l) {
  __builtin_amdgcn_global_load_lds((gas1_t)g, (las3_t)l, 16, 0, 0);
}

// ============ bf16 MFMA GEMM, 64x128 tile, depth-2 pipelined K-loop ============
__global__ __launch_bounds__(256) void mfma_gemm(
    const ushort_t* __restrict__ A, const ushort_t* __restrict__ A2, int lda,
    const ushort_t* __restrict__ W, const ushort_t* __restrict__ W2, int ldw,
    const float* __restrict__ bias, const float* __restrict__ bias2,
    float* __restrict__ C, float* __restrict__ C2, int ldc,
    int M, int K, int nkChunks, long partStride, int epi)
{
  int z = blockIdx.z;
  int dir = z / nkChunks, chunk = z - dir * nkChunks;
  if (dir) { A = A2; W = W2; C = C2; bias = bias2; }
  int kChunk = K / nkChunks;
  int kbeg = chunk * kChunk;
  if (nkChunks > 1) C += (long)chunk * partStride;

  __shared__ __align__(16) ushort_t At[3 * ABUF];
  __shared__ __align__(16) ushort_t Bt[3 * BBUF];

  int tid = threadIdx.x, wv = tid >> 6, lane = tid & 63;
  int m0 = blockIdx.y * 64, n0 = blockIdx.x * 128;

  int rA = tid >> 2, gA = (tid & 3) ^ ((rA >> 1) & 3);
  const ushort_t* aSrc = A + (size_t)min(m0 + rA, M - 1) * lda + gA * 8 + kbeg;
  int aOff = tid * 8;
  int SB0 = tid, SB1 = tid + 256;
  int rB0 = SB0 >> 2, gB0 = (SB0 & 3) ^ ((rB0 >> 1) & 3);
  int rB1 = SB1 >> 2, gB1 = (SB1 & 3) ^ ((rB1 >> 1) & 3);
  const ushort_t* bSrc0 = W + (size_t)(n0 + rB0) * ldw + gB0 * 8 + kbeg;
  const ushort_t* bSrc1 = W + (size_t)(n0 + rB1) * ldw + gB1 * 8 + kbeg;
  int bOff0 = SB0 * 8, bOff1 = SB1 * 8;

  int wr = wv >> 1, wc = wv & 1;
  int rl = lane & 15, gl = lane >> 4;
  int offA[2], offB[4];
#pragma unroll
  for (int i = 0; i < 2; ++i) {
    int ra = wr * 32 + i * 16 + rl;
    offA[i] = ra * 32 + ((gl ^ ((ra >> 1) & 3)) * 8);
  }
#pragma unroll
  for (int j = 0; j < 4; ++j) {
    int rb = wc * 64 + j * 16 + rl;
    offB[j] = rb * 32 + ((gl ^ ((rb >> 1) & 3)) * 8);
  }

  f32x4 acc[2][4] = {};
  int nk = kChunk >> 5;
  gll16(aSrc, At + aOff);
  gll16(bSrc0, Bt + bOff0);
  gll16(bSrc1, Bt + bOff1);
  if (nk > 1) {
    gll16(aSrc + 32, At + ABUF + aOff);
    gll16(bSrc0 + 32, Bt + BBUF + bOff0);
    gll16(bSrc1 + 32, Bt + BBUF + bOff1);
  }
  int bufT = 0;
  for (int t = 0; t < nk; ++t) {
    int bufN = bufT + 2; if (bufN >= 3) bufN -= 3;
    if (t + 2 < nk) {
      int ko = (t + 2) << 5;
      gll16(aSrc + ko, At + bufN * ABUF + aOff);
      gll16(bSrc0 + ko, Bt + bufN * BBUF + bOff0);
      gll16(bSrc1 + ko, Bt + bufN * BBUF + bOff1);
      asm volatile("s_waitcnt vmcnt(6)" ::: "memory");
    } else if (t + 1 < nk) {
      asm volatile("s_waitcnt vmcnt(3)" ::: "memory");
    } else {
      asm volatile("s_waitcnt vmcnt(0)" ::: "memory");
    }
    __builtin_amdgcn_s_barrier();
    __builtin_amdgcn_sched_barrier(0);
    const ushort_t* Ab = At + bufT * ABUF;
    const ushort_t* Bb = Bt + bufT * BBUF;
    bf16x8 af[2], bw[4];
#pragma unroll
    for (int i = 0; i < 2; ++i) af[i] = *(const bf16x8*)(Ab + offA[i]);
#pragma unroll
    for (int j = 0; j < 4; ++j) bw[j] = *(const bf16x8*)(Bb + offB[j]);
#pragma unroll
    for (int i = 0; i < 2; ++i)
#pragma unroll
      for (int j = 0; j < 4; ++j)
        acc[i][j] = __builtin_amdgcn_mfma_f32_16x16x32_bf16(af[i], bw[j], acc[i][j], 0, 0, 0);
    asm volatile("s_waitcnt lgkmcnt(0)" ::: "memory");
    __builtin_amdgcn_s_barrier();
    __builtin_amdgcn_sched_barrier(0);
    bufT += 1; if (bufT == 3) bufT = 0;
  }

#pragma unroll
  for (int i = 0; i < 2; ++i) {
    int row0 = m0 + wr * 32 + i * 16 + gl * 4;
#pragma unroll
    for (int q = 0; q < 4; ++q) {
      int row = row0 + q;
      if (row >= M) continue;
#pragma unroll
      for (int j = 0; j < 4; ++j) {
        int col = n0 + wc * 64 + j * 16 + rl;
        float v = acc[i][j][q];
        if (bias) v += bias[col];
        if (epi & 1) v = (v > 20.f) ? v : log1pf(__expf(v));
        if (epi & 2) ((ushort_t*)C)[(size_t)row * ldc + col] = f2bf(v);
        else C[(size_t)row * ldc + col] = v;
      }
    }
  }
}

// ===================== merged weight cast, 2 units (64B) per thread =====================
__device__ __forceinline__ void cast_unit(
    int u,
    const float* __restrict__ in_w, const float* __restrict__ out_w,
    const float* __restrict__ xw0, const float* __restrict__ xwb0,
    const float* __restrict__ pvw, const float* __restrict__ paw,
    ushort_t* __restrict__ WALL, ushort_t* __restrict__ wPv, ushort_t* __restrict__ wPa)
{
  const float* src = nullptr;
  ushort_t* dst;
  if (u < U_WIN) { src = in_w + (size_t)u * 8; dst = WALL + (size_t)u * 8; }
  else {
    int u2 = u - U_WIN;
    if (u2 < U_WOUT) { src = out_w + (size_t)u2 * 8; dst = WALL + WIN_SZ + (size_t)u2 * 8; }
    else {
      u2 -= U_WOUT;
      if (u2 < U_WX) {
        int ld = u2 / 24576;
        int j = (u2 - ld * 24576) * 8;
        int l = ld >> 1;
        const float* xs = ((ld & 1) ? xwb0 : xw0) + (size_t)l * 122880;
        int r = j / 1536, k = j - r * 1536;
        if (r < 80) src = xs + r * 1536 + k;
        dst = WALL + WIN_SZ + WOUT_SZ + (size_t)ld * 196608 + j;
      } else {
        u2 -= U_WX;
        if (u2 < U_WPV) { src = pvw + (size_t)u2 * 8; dst = wPv + (size_t)u2 * 8; }
        else { u2 -= U_WPV; src = paw + (size_t)u2 * 8; dst = wPa + (size_t)u2 * 8; }
      }
    }
  }
  f32x4 v0 = {0.f,0.f,0.f,0.f}, v1 = {0.f,0.f,0.f,0.f};
  if (src) { v0 = *(const f32x4*)src; v1 = *(const f32x4*)(src + 4); }
  us8 o = { f2bf(v0[0]), f2bf(v0[1]), f2bf(v0[2]), f2bf(v0[3]),
            f2bf(v1[0]), f2bf(v1[1]), f2bf(v1[2]), f2bf(v1[3]) };
  *(us8*)dst = o;
}

__global__ __launch_bounds__(256) void castall_k(
    const float* __restrict__ in_w, const float* __restrict__ out_w,
    const float* __restrict__ xw0, const float* __restrict__ xwb0,
    const float* __restrict__ pvw, const float* __restrict__ paw,
    ushort_t* __restrict__ WALL, ushort_t* __restrict__ wPv, ushort_t* __restrict__ wPa)
{
  int i = blockIdx.x * 256 + threadIdx.x;
#pragma unroll
  for (int s = 0; s < 2; ++s) {
    int u = i * 2 + s;
    if (u < U_ALL)
      cast_unit(u, in_w, out_w, xw0, xwb0, pvw, paw, WALL, wPv, wPa);
  }
}

// ===================== fallback casts (small-ws path only) =====================
__global__ __launch_bounds__(256) void cast4_k(const float* __restrict__ s, ushort_t* __restrict__ d, int n4)
{
  int i = blockIdx.x * 256 + threadIdx.x;
  if (i >= n4) return;
  f32x4 v = *(const f32x4*)(s + i * 4);
  us4 o = { f2bf(v[0]), f2bf(v[1]), f2bf(v[2]), f2bf(v[3]) };
  *(us4*)(d + i * 4) = o;
}

__global__ __launch_bounds__(256) void cast8_k(const float* __restrict__ s, ushort_t* __restrict__ d, int n8)
{
  int i = blockIdx.x * 256 + threadIdx.x;
  if (i >= n8) return;
  f32x4 v0 = *(const f32x4*)(s + i * 8);
  f32x4 v1 = *(const f32x4*)(s + i * 8 + 4);
  us8 o = { f2bf(v0[0]), f2bf(v0[1]), f2bf(v0[2]), f2bf(v0[3]),
            f2bf(v1[0]), f2bf(v1[1]), f2bf(v1[2]), f2bf(v1[3]) };
  *(us8*)(d + i * 8) = o;
}

__global__ __launch_bounds__(256) void castx8_k(
    const float* __restrict__ xw0, const float* __restrict__ xwb0,
    ushort_t* __restrict__ WX, int nl)
{
  int i = blockIdx.x * 256 + threadIdx.x;
  if (i >= nl * 2 * 24576) return;
  int ld = i / 24576;
  int j = (i - ld * 24576) * 8;
  int l = ld >> 1;
  const float* xs = ((ld & 1) ? xwb0 : xw0) + (size_t)l * 122880;
  int r = j / 1536, k = j - r * 1536;
  f32x4 v0 = {0.f,0.f,0.f,0.f}, v1 = {0.f,0.f,0.f,0.f};
  if (r < 80) { v0 = *(const f32x4*)(xs + r * 1536 + k); v1 = *(const f32x4*)(xs + r * 1536 + k + 4); }
  us8 o = { f2bf(v0[0]), f2bf(v0[1]), f2bf(v0[2]), f2bf(v0[3]),
            f2bf(v1[0]), f2bf(v1[1]), f2bf(v1[2]), f2bf(v1[3]) };
  *(us8*)(WX + (size_t)ld * 196608 + j) = o;
}

// ===================== merged im2col (video + audio) =====================
__global__ __launch_bounds__(256) void im2col_va(
    const float* __restrict__ xv, ushort_t* __restrict__ Av,
    const float* __restrict__ xa, ushort_t* __restrict__ Aa)
{
  int i = blockIdx.x * 256 + threadIdx.x;
  if (i < 1568 * 768) {
    int m = i / 768, k = i % 768;
    int c = k >> 8, r = k & 255;
    int kh = r >> 4, kw = r & 15;
    int bt = m / 196, n = m % 196;
    int b = bt / TT, t = bt % TT;
    int hb = n / 14, wb = n % 14;
    Av[i] = f2bf(xv[(size_t)b * 602112 + (size_t)c * 200704 + t * 50176 + (hb * 16 + kh) * 224 + wb * 16 + kw]);
    return;
  }
  i -= 1568 * 768;
  if (i >= 192 * 256) return;
  int m = i / 256, k = i % 256;
  int kh = k >> 4, kw = k & 15;
  int b = m / 96, q = m % 96;
  int tb = q >> 2, fb = q & 3;
  Aa[i] = f2bf(xa[(size_t)b * 24576 + (fb * 16 + kw) * 384 + tb * 16 + kh]);
}

// ===================== assemble tokens + gather =====================
__global__ __launch_bounds__(256) void assemble_k(
    const float* __restrict__ tokv, const float* __restrict__ toka,
    const float* __restrict__ pos_v, const float* __restrict__ pos_a,
    const float* __restrict__ tpos_v, const float* __restrict__ tpos_a,
    const float* __restrict__ cls_v, const float* __restrict__ cls_a,
    const float* __restrict__ glob_v, const float* __restrict__ glob_a,
    const int* __restrict__ vis_idx,
    float* __restrict__ h, float* __restrict__ res)
{
  int i = blockIdx.x * 256 + threadIdx.x;
  if (i >= NROWS * DD) return;
  int d = i % DD;
  int bl = i / DD;
  int r = bl % LV, b = bl / LV;
  int tok = vis_idx[b * LV + r];
  int t = tok / 224, q = tok % 224;
  float v;
  if (q == 0) v = cls_v[d];
  else if (q <= 196) {
    int n = q - 1;
    v = tokv[((size_t)(b * TT + t) * 196 + n) * DD + d] + pos_v[n * DD + d] + tpos_v[t * DD + d];
  } else if (q == 197) v = glob_v[d];
  else if (q == 198) v = cls_a[d];
  else if (q <= 222) {
    int n = q - 199;
    v = toka[((size_t)b * 96 + t * 24 + n) * DD + d] + pos_a[n * DD + d] + tpos_a[t * DD + d];
  } else v = glob_a[d];
  h[i] = v;
  res[i] = 0.f;
}

// ============ fused (out-proj split-K reduce OR h read) + residual + RMSNorm ============
__global__ __launch_bounds__(256) void rmsnorm_k(
    const float* __restrict__ hsrc, const float* __restrict__ part,
    float* __restrict__ res, ushort_t* __restrict__ hn, const float* __restrict__ nw)
{
  int row = blockIdx.x;
  float* rp = res + (size_t)row * DD;
  ushort_t* op = hn + (size_t)row * DD;
  int tid = threadIdx.x;
  float v[3];
  float ss = 0.f;
#pragma unroll
  for (int i = 0; i < 3; ++i) {
    int c = tid + i * 256;
    float x;
    if (part) {
      x = part[(size_t)row * DD + c] + part[688128 + (size_t)row * DD + c]
        + part[2 * 688128 + (size_t)row * DD + c] + part[3 * 688128 + (size_t)row * DD + c];
    } else {
      x = hsrc[(size_t)row * DD + c];
    }
    x += rp[c];
    v[i] = x;
    ss += x * x;
  }
  for (int m = 1; m < 64; m <<= 1) ss += __shfl_xor(ss, m, 64);
  __shared__ float sred[4];
  if ((tid & 63) == 0) sred[tid >> 6] = ss;
  __syncthreads();
  float tot = sred[0] + sred[1] + sred[2] + sred[3];
  float sc = rsqrtf(tot / (float)DD + 1e-5f);
#pragma unroll
  for (int i = 0; i < 3; ++i) {
    int c = tid + i * 256;
    rp[c] = v[i];
    op[c] = f2bf(v[i] * sc * nw[c]);
  }
}

// ======== causal depthwise conv (k=4, bf16 in) + silu -> bf16, 4 channels/thread ========
__global__ __launch_bounds__(256) void conv_k(
    const ushort_t* __restrict__ xz,
    const float* __restrict__ cw, const float* __restrict__ cb,
    const float* __restrict__ cwb, const float* __restrict__ cbb,
    ushort_t* __restrict__ xcFb, ushort_t* __restrict__ xcBb)
{
  int i = blockIdx.x * 256 + threadIdx.x;
  if (i >= NROWS * (DI_ / 4)) return;
  int dv = (i % (DI_ / 4)) * 4;
  int bl = i / (DI_ / 4);
  int l = bl % LV, b = bl / LV;
  const ushort_t* xzb = xz + (size_t)b * LV * (2 * DI_);
  f32x4 accf = *(const f32x4*)(cb + dv);
  f32x4 accb = *(const f32x4*)(cbb + dv);
  f32x4 tf[4], tb[4];
#pragma unroll
  for (int e = 0; e < 4; ++e) {
    tf[e] = *(const f32x4*)(cw + (dv + e) * 4);
    tb[e] = *(const f32x4*)(cwb + (dv + e) * 4);
  }
#pragma unroll
  for (int j = 0; j < 4; ++j) {
    int lp = l - 3 + j;
    if (lp >= 0) {
      us4 xf = *(const us4*)(xzb + (size_t)lp * (2 * DI_) + dv);
      us4 xb = *(const us4*)(xzb + (size_t)(LV - 1 - lp) * (2 * DI_) + dv);
#pragma unroll
      for (int e = 0; e < 4; ++e) {
        accf[e] += bf2f(xf[e]) * tf[e][j];
        accb[e] += bf2f(xb[e]) * tb[e][j];
      }
    }
  }
  us4 of, ob;
#pragma unroll
  for (int e = 0; e < 4; ++e) {
    of[e] = f2bf(silu_f(accf[e]));
    ob[e] = f2bf(silu_f(accb[e]));
  }
  *(us4*)(xcFb + (size_t)bl * DI_ + dv) = of;
  *(us4*)(xcBb + (size_t)bl * DI_ + dv) = ob;
}

// ======== fused split-K reduce + dt "GEMM" (K=48) + softplus -> bf16 dt ========
__global__ __launch_bounds__(256) void reddt_k(
    const float* __restrict__ pF, const float* __restrict__ pB,
    float* __restrict__ prF, float* __restrict__ prB,
    const float* __restrict__ dwF, const float* __restrict__ dwB,
    const float* __restrict__ dbF, const float* __restrict__ dbB,
    ushort_t* __restrict__ dtFb, ushort_t* __restrict__ dtBb)
{
  int dir = blockIdx.y;
  const float* part = dir ? pB : pF;
  float* proj = dir ? prB : prF;
  const float* dw = dir ? dwB : dwF;
  const float* db = dir ? dbB : dbF;
  ushort_t* dt = dir ? dtBb : dtFb;
  int r0 = blockIdx.x * 8;
  int tid = threadIdx.x;
  __shared__ float sdtr[8][48];
  for (int o = tid; o < 8 * 80; o += 256) {
    int r = o / 80, col = o - (o / 80) * 80;
    int row = r0 + r;
    float s = 0.f;
#pragma unroll
    for (int c = 0; c < 8; ++c) s += part[c * (NROWS * 128) + row * 128 + col];
    proj[row * 80 + col] = s;
    if (col < 48) sdtr[r][col] = s;
  }
  __syncthreads();
#pragma unroll
  for (int q = 0; q < 6; ++q) {
    int d = q * 256 + tid;
    f32x4 w[12];
#pragma unroll
    for (int e = 0; e < 12; ++e) w[e] = *(const f32x4*)(dw + (size_t)d * 48 + e * 4);
    float bias = db[d];
#pragma unroll
    for (int r = 0; r < 8; ++r) {
      float s = bias;
#pragma unroll
      for (int e = 0; e < 12; ++e) {
#pragma unroll
        for (int u = 0; u < 4; ++u) s += sdtr[r][e * 4 + u] * w[e][u];
      }
      s = (s > 20.f) ? s : log1pf(__expf(s));
      dt[(size_t)(r0 + r) * DI_ + d] = f2bf(s);
    }
  }
}

// ===================== chunked selective scan (CLEN=32, NCH=14) ===========
__global__ __launch_bounds__(256) void scanA_k(
    const ushort_t* __restrict__ xcFb, const ushort_t* __restrict__ dtF, const float* __restrict__ prF,
    const ushort_t* __restrict__ xcBb, const ushort_t* __restrict__ dtB, const float* __restrict__ prB,
    const float* __restrict__ AlF, const float* __restrict__ AlB,
    float* __restrict__ hloc, float* __restrict__ Pb)
{
  int dir = blockIdx.z;
  const ushort_t* xc = dir ? xcBb : xcFb;
  const ushort_t* dt = dir ? dtB : dtF;
  const float* pr = dir ? prB : prF;
  const float* Al = dir ? AlB : AlF;
  int c = blockIdx.y;
  int g = blockIdx.x * 16 + (threadIdx.x >> 4);
  int n = threadIdx.x & 15;
  int b = g / DI_, d = g % DI_;
  float An = -__expf(Al[d * NS_ + n]);
  const ushort_t* xcp = xc + (size_t)b * LV * DI_ + d;
  const ushort_t* dtp = dt + (size_t)b * LV * DI_ + d;
  const float* prp = pr + (size_t)b * LV * 80;
  int l0 = c * CLEN;
  float hs = 0.f, S = 0.f;
  float dtv = bf2f(dtp[(size_t)l0 * DI_]);
  float xcv = bf2f(xcp[(size_t)l0 * DI_]);
  float bn  = prp[l0 * 80 + 48 + n];
  for (int kk = 0; kk < CLEN; ++kk) {
    float dtv_n = 0.f, xcv_n = 0.f, bn_n = 0.f;
    if (kk < CLEN - 1) {
      int l1 = l0 + kk + 1;
      dtv_n = bf2f(dtp[(size_t)l1 * DI_]);
      xcv_n = bf2f(xcp[(size_t)l1 * DI_]);
      bn_n  = prp[l1 * 80 + 48 + n];
    }
    hs = __expf(dtv * An) * hs + dtv * bn * xcv;
    S += dtv;
    dtv = dtv_n; xcv = xcv_n; bn = bn_n;
  }
  int idx = ((dir * 3072 + g) * NCHA + c) * NS_ + n;
  hloc[idx] = hs;
  Pb[idx] = __expf(An * S);
}

// pass BC: both dirs in parallel warps; in-block h_start prefix; fused combine.
__global__ __launch_bounds__(256) void scanBC_k(
    const ushort_t* __restrict__ xcFb, const ushort_t* __restrict__ dtF, const float* __restrict__ prF,
    const ushort_t* __restrict__ xcBb, const ushort_t* __restrict__ dtB, const float* __restrict__ prB,
    const float* __restrict__ AlF, const float* __restrict__ AlB,
    const float* __restrict__ DpF, const float* __restrict__ DpB,
    const float* __restrict__ hloc, const float* __restrict__ Pb,
    const ushort_t* __restrict__ xz, ushort_t* __restrict__ yc)
{
  int c = blockIdx.y;                 // fwd chunk index
  int tid = threadIdx.x;
  int n = tid & 15, gi = (tid >> 4) & 7, dir = tid >> 7;
  int g = blockIdx.x * 8 + gi;
  int b = g / DI_, d = g % DI_;
  __shared__ float sbuf[2][8][CLEN + 1];

  const ushort_t* xc = dir ? xcBb : xcFb;
  const ushort_t* dt = dir ? dtB : dtF;
  const float* pr = dir ? prB : prF;
  const float* Al = dir ? AlB : AlF;
  const float* Dpp = dir ? DpB : DpF;
  int myc = dir ? (NCH - 1 - c) : c;  // chunk in own time direction
  float An = -__expf(Al[d * NS_ + n]);
  float Dpd = Dpp[d];
  float hs = 0.f;
  for (int j = 0; j < myc; ++j) {
    int idx = ((dir * 3072 + g) * NCHA + j) * NS_ + n;
    hs = Pb[idx] * hs + hloc[idx];
  }
  const ushort_t* xcp = xc + (size_t)b * LV * DI_ + d;
  const ushort_t* dtp = dt + (size_t)b * LV * DI_ + d;
  const float* prp = pr + (size_t)b * LV * 80;
  int l0 = myc * CLEN;
  float dtv = bf2f(dtp[(size_t)l0 * DI_]);
  float xcv = bf2f(xcp[(size_t)l0 * DI_]);
  float bn  = prp[l0 * 80 + 48 + n];
  float cn  = prp[l0 * 80 + 64 + n];
  for (int kk = 0; kk < CLEN; ++kk) {
    float dtv_n = 0.f, xcv_n = 0.f, bn_n = 0.f, cn_n = 0.f;
    if (kk < CLEN - 1) {
      int l1 = l0 + kk + 1;
      dtv_n = bf2f(dtp[(size_t)l1 * DI_]);
      xcv_n = bf2f(xcp[(size_t)l1 * DI_]);
      bn_n  = prp[l1 * 80 + 48 + n];
      cn_n  = prp[l1 * 80 + 64 + n];
    }
    hs = __expf(dtv * An) * hs + dtv * bn * xcv;
    float p = hs * cn;
    p += __shfl_xor(p, 1, 16);
    p += __shfl_xor(p, 2, 16);
    p += __shfl_xor(p, 4, 16);
    p += __shfl_xor(p, 8, 16);
    if (n == 0) {
      int off = dir ? (CLEN - 1 - kk) : kk;
      sbuf[dir][gi][off] = p + xcv * Dpd;
    }
    dtv = dtv_n; xcv = xcv_n; bn = bn_n; cn = cn_n;
  }
  __syncthreads();
  // combine: consecutive lanes -> consecutive d (coalesced)
  for (int oid = tid; oid < 8 * CLEN; oid += 256) {
    int gi2 = oid & 7, kk = oid >> 3;
    int g2 = blockIdx.x * 8 + gi2;
    int b2 = g2 / DI_, d2 = g2 % DI_;
    int l = c * CLEN + kk;
    float z = bf2f(xz[((size_t)b2 * LV + l) * 3072 + 1536 + d2]);
    float v = (sbuf[0][gi2][kk] + sbuf[1][gi2][kk]) * silu_f(z);
    yc[((size_t)b2 * LV + l) * DI_ + d2] = f2bf(v);
  }
}

// ===================== final: out = res + sum(partO) ==============
__global__ __launch_bounds__(256) void final_k(
    const float* __restrict__ res, const float* __restrict__ part, float* __restrict__ out)
{
  int i = blockIdx.x * 256 + threadIdx.x;
  if (i >= NROWS * DD) return;
  out[i] = res[i] + part[i] + part[688128 + i] + part[2 * 688128 + i] + part[3 * 688128 + i];
}

extern "C" void kernel_launch(void* const* d_in, const int* in_sizes, int n_in,
                              void* d_out, int out_size, void* d_ws, size_t ws_size,
                              hipStream_t stream)
{
  const float* x_v = (const float*)d_in[0];
  const float* x_a = (const float*)d_in[1];
  const float* patch_v_w = (const float*)d_in[2];
  const float* patch_v_b = (const float*)d_in[3];
  const float* patch_a_w = (const float*)d_in[4];
  const float* patch_a_b = (const float*)d_in[5];
  const float* pos_v = (const float*)d_in[6];
  const float* pos_a = (const float*)d_in[7];
  const float* tpos_v = (const float*)d_in[8];
  const float* tpos_a = (const float*)d_in[9];
  const float* cls_v = (const float*)d_in[10];
  const float* cls_a = (const float*)d_in[11];
  const float* glob_v = (const float*)d_in[12];
  const float* glob_a = (const float*)d_in[13];
  const float* norm_w = (const float*)d_in[14];
  const float* in_w = (const float*)d_in[15];
  const float* conv_w = (const float*)d_in[16];
  const float* conv_b = (const float*)d_in[17];
  const float* conv_w_b = (const float*)d_in[18];
  const float* conv_b_b = (const float*)d_in[19];
  const float* xproj_w = (const float*)d_in[20];
  const float* xproj_w_b = (const float*)d_in[21];
  const float *dt_w, *dt_bias, *dt_w_b, *dt_bias_b;
  if (in_sizes[23] == DEPTH_ * DI_ * RK_) {  // dict order: dt_w, dt_w_b, dt_b, dt_b_b
    dt_w = (const float*)d_in[22]; dt_w_b = (const float*)d_in[23];
    dt_bias = (const float*)d_in[24]; dt_bias_b = (const float*)d_in[25];
  } else {                                   // signature order
    dt_w = (const float*)d_in[22]; dt_bias = (const float*)d_in[23];
    dt_w_b = (const float*)d_in[24]; dt_bias_b = (const float*)d_in[25];
  }
  const float* A_log = (const float*)d_in[26];
  const float* A_log_b = (const float*)d_in[27];
  const float* D_par = (const float*)d_in[28];
  const float* D_par_b = (const float*)d_in[29];
  const float* out_w = (const float*)d_in[30];
  const int* vis_idx = (const int*)d_in[31];

  // ---------------- workspace layout (float units) ----------------
  float* ws = (float*)d_ws;
  float* res   = ws;                 // 688128
  float* hbuf  = ws + 688128;        // 688128 (phase-1 h only)
  float* R1    = ws + 1376256;       // 2752512: phase1 | xproj partials | hloc+Pb | outproj partials
  float* R2f   = ws + 4128768;       // 688128: hn_bf | ycb
  float* R3    = ws + 4816896;       // 1376256: xcFb + xcBb (bf16)
  float* xz    = ws + 7569408;       // 896*3072 bf16 (phase1: Av_bf alias)
  float* dtFf  = ws + 10321920;      // 896*1536 bf16
  float* dtBf  = ws + 11698176;      // 896*1536 bf16
  float* projF = ws + 13074432;      // 71680
  float* projB = ws + 13146112;      // 71680
  float* wPvf  = ws + 13217792;      // 294912 (589824 bf16)
  float* WALLf = ws + 13512704;      // WALL_USH ushorts

  // R1 views
  float* partF = R1;                         // 8*896*128 = 917504
  float* partB = R1 + 917504;
  float* hloc  = R1;                         // 2*3072*13*16 = 1277952
  float* Pb    = R1 + 1277952;               // 1277952
  float* partO = R1;                         // 4*688128 = 2752512
  // phase-1 views
  float* tokv  = R1;                         // 1568*768
  float* toka  = R1 + 1204224;               // 192*768
  ushort_t* Av_bf = (ushort_t*)xz;           // 1568*768 bf16
  ushort_t* wPv   = (ushort_t*)wPvf;
  ushort_t* wPa   = (ushort_t*)dtFf;         // 768*256 bf16 (dead in phase 1)
  ushort_t* Aa_bf = ((ushort_t*)dtFf) + 196608;
  // R2 views
  ushort_t* hn_bf = (ushort_t*)R2f;          // 896*768
  ushort_t* ycb   = (ushort_t*)R2f;          // 896*1536
  // R3 views
  ushort_t* xcFb = (ushort_t*)R3;            // 896*1536
  ushort_t* xcBb = ((ushort_t*)R3) + 1376256;
  ushort_t* xzb  = (ushort_t*)xz;            // 896*3072 bf16
  ushort_t* dtFb = (ushort_t*)dtFf;
  ushort_t* dtBb = (ushort_t*)dtBf;

  size_t need_big = ((size_t)13512704 + (WALL_USH + 1) / 2) * 4;
  int bigws = ws_size >= need_big;
  ushort_t* WALL = (ushort_t*)WALLf;
  ushort_t* WIN  = WALL;
  ushort_t* WOUT = WIN + WIN_SZ;
  ushort_t* WX   = WOUT + WOUT_SZ;

  dim3 blk(256);

  // ---- single merged weight cast (all regions, incl. patch weights) ----
  if (bigws) {
    castall_k<<<(U_ALL / 2 + 255) / 256, blk, 0, stream>>>(
        in_w, out_w, xproj_w, xproj_w_b, patch_v_w, patch_a_w, WALL, wPv, wPa);
  } else {
    cast4_k<<<576, blk, 0, stream>>>(patch_v_w, wPv, 147456);
    cast4_k<<<192, blk, 0, stream>>>(patch_a_w, wPa, 49152);
  }

  // ---- phase 1: patch embed + assemble ----
  im2col_va<<<4896, blk, 0, stream>>>(x_v, Av_bf, x_a, Aa_bf);
  mfma_gemm<<<dim3(6, 25, 1), blk, 0, stream>>>(Av_bf, nullptr, 768, wPv, nullptr, 768,
                                                patch_v_b, nullptr, tokv, nullptr, 768,
                                                1568, 768, 1, 0, 0);
  mfma_gemm<<<dim3(6, 3, 1), blk, 0, stream>>>(Aa_bf, nullptr, 256, wPa, nullptr, 256,
                                               patch_a_b, nullptr, toka, nullptr, 768,
                                               192, 256, 1, 0, 0);
  assemble_k<<<2688, blk, 0, stream>>>(tokv, toka, pos_v, pos_a, tpos_v, tpos_a,
                                       cls_v, cls_a, glob_v, glob_a, vis_idx, hbuf, res);

  // ---- phase 2: layers 0..14 (layer 15's compute is dead except res += h) ----
  for (int l = 0; l < NRUN; ++l) {
    const float* nw  = norm_w + l * DD;
    const float* cw  = conv_w + l * DI_ * KC_;
    const float* cb  = conv_b + l * DI_;
    const float* cwb = conv_w_b + l * DI_ * KC_;
    const float* cbb = conv_b_b + l * DI_;
    const float* dwF = dt_w + (size_t)l * DI_ * RK_;
    const float* dwB = dt_w_b + (size_t)l * DI_ * RK_;
    const float* dbi = dt_bias + l * DI_;
    const float* dbib = dt_bias_b + l * DI_;
    const float* al  = A_log + (size_t)l * DI_ * NS_;
    const float* alb = A_log_b + (size_t)l * DI_ * NS_;
    const float* dp  = D_par + l * DI_;
    const float* dpb = D_par_b + l * DI_;

    ushort_t *wIn, *wOut, *wXF, *wXB;
    if (bigws) {
      wIn  = WIN + (size_t)l * 2359296;
      wOut = WOUT + (size_t)l * 1179648;
      wXF  = WX + (size_t)(l * 2) * 196608;
      wXB  = wXF + 196608;
    } else {
      wIn = WALL; wOut = wIn + 2359296; wXF = wOut + 1179648; wXB = wXF + 196608;
      cast8_k<<<(2359296 / 8 + 255) / 256, blk, 0, stream>>>(in_w + (size_t)l * 2359296, wIn, 2359296 / 8);
      cast8_k<<<(1179648 / 8 + 255) / 256, blk, 0, stream>>>(out_w + (size_t)l * 1179648, wOut, 1179648 / 8);
      castx8_k<<<(2 * 24576 + 255) / 256, blk, 0, stream>>>(xproj_w + (size_t)l * 122880,
                                                            xproj_w_b + (size_t)l * 122880, wXF, 1);
    }

    // residual add + RMSNorm (fuses previous layer's out-proj split-K reduce)
    rmsnorm_k<<<NROWS, blk, 0, stream>>>(hbuf, l ? partO : nullptr, res, hn_bf, nw);
    // in-proj: [896,3072] = hn @ in_w^T, bf16 out
    mfma_gemm<<<dim3(24, 14, 1), blk, 0, stream>>>(hn_bf, nullptr, 768, wIn, nullptr, 768,
                                                   nullptr, nullptr, (float*)xzb, nullptr, 3072,
                                                   NROWS, 768, 1, 0, 2);
    conv_k<<<1344, blk, 0, stream>>>(xzb, cw, cb, cwb, cbb, xcFb, xcBb);
    // xproj both dirs, split-K x8
    mfma_gemm<<<dim3(1, 14, 16), blk, 0, stream>>>(xcFb, xcBb, 1536, wXF, wXB, 1536,
                                                   nullptr, nullptr, partF, partB, 128,
                                                   NROWS, 1536, 8, NROWS * 128, 0);
    // fused reduce + dt(+softplus) -> bf16
    reddt_k<<<dim3(112, 2, 1), blk, 0, stream>>>(partF, partB, projF, projB,
                                                 dwF, dwB, dbi, dbib, dtFb, dtBb);
    // chunked scan: passA (13 chunks of 32) then fused passB+combine (14 chunks)
    scanA_k<<<dim3(192, NCHA, 2), blk, 0, stream>>>(xcFb, dtFb, projF, xcBb, dtBb, projB,
                                                    al, alb, hloc, Pb);
    scanBC_k<<<dim3(384, NCH, 1), blk, 0, stream>>>(xcFb, dtFb, projF, xcBb, dtBb, projB,
                                                    al, alb, dp, dpb, hloc, Pb, xzb, ycb);
    // out-proj split-K x4: partials reduced by next layer's rmsnorm (or final_k)
    mfma_gemm<<<dim3(6, 14, 4), blk, 0, stream>>>(ycb, nullptr, 1536, wOut, nullptr, 1536,
                                                  nullptr, nullptr, partO, nullptr, 768,
                                                  NROWS, 1536, 4, NROWS * DD, 0);
  }

  final_k<<<2688, blk, 0, stream>>>(res, partO, (float*)d_out);
}

// Round 13
// 2526.578 us; speedup vs baseline: 1.0688x; 1.0688x over previous
//
#include <hip/hip_runtime.h>
#include <math.h>

typedef unsigned short ushort_t;
typedef __attribute__((ext_vector_type(8))) short bf16x8;
typedef __attribute__((ext_vector_type(4))) float f32x4;
typedef __attribute__((ext_vector_type(4))) unsigned short us4;
typedef __attribute__((ext_vector_type(8))) unsigned short us8;

#define NBATCH 2
#define TT 4
#define DD 768
#define DI_ 1536
#define NS_ 16
#define RK_ 48
#define KC_ 4
#define DEPTH_ 16
#define NRUN 15             // layer 16's compute is dead (only res += h survives)
#define LV 448
#define NROWS (NBATCH*LV)   // 896
#define NCH 7               // scan chunks
#define CLEN 64             // chunk length (7*64 = 448)

// bf16 weight arena (ushorts): WIN[15*2359296] | WOUT[15*1179648] | WX[15*2*196608]
#define WIN_SZ   (NRUN*2359296)
#define WOUT_SZ  (NRUN*1179648)
#define WX_SZ    (NRUN*2*196608)
#define WALL_USH (WIN_SZ + WOUT_SZ + WX_SZ)

#define ABUF 2048   // 64*32 ushorts per A buffer
#define BBUF 4096   // 128*32 ushorts per B buffer

// castall unit counts (8 ushorts per unit)
#define U_WIN  (WIN_SZ/8)
#define U_WOUT (WOUT_SZ/8)
#define U_WX   (WX_SZ/8)
#define U_WPV  (589824/8)
#define U_WPA  (196608/8)
#define U_ALL  (U_WIN+U_WOUT+U_WX+U_WPV+U_WPA)

__device__ __forceinline__ float silu_f(float x) { return x / (1.f + __expf(-x)); }
__device__ __forceinline__ ushort_t f2bf(float x) {
  unsigned int u = __float_as_uint(x);
  return (ushort_t)((u + 0x7FFFu + ((u >> 16) & 1u)) >> 16);
}
__device__ __forceinline__ float bf2f(ushort_t h) {
  return __uint_as_float(((unsigned int)h) << 16);
}

typedef const __attribute__((address_space(1))) unsigned int* gas1_t;
typedef __attribute__((address_space(3))) unsigned int* las3_t;
__device__ __forceinline__ void gll16(const ushort_t* g, ushort_t* l) {
  __builtin_amdgcn_global_load_lds((gas1_t)g, (las3_t)l, 16, 0, 0);
}

// ============ bf16 MFMA GEMM, 64x128 tile, depth-2 pipelined K-loop ============
__global__ __launch_bounds__(256) void mfma_gemm(
    const ushort_t* __restrict__ A, const ushort_t* __restrict__ A2, int lda,
    const ushort_t* __restrict__ W, const ushort_t* __restrict__ W2, int ldw,
    const float* __restrict__ bias, const float* __restrict__ bias2,
    float* __restrict__ C, float* __restrict__ C2, int ldc,
    int M, int K, int nkChunks, long partStride, int epi)
{
  int z = blockIdx.z;
  int dir = z / nkChunks, chunk = z - dir * nkChunks;
  if (dir) { A = A2; W = W2; C = C2; bias = bias2; }
  int kChunk = K / nkChunks;
  int kbeg = chunk * kChunk;
  if (nkChunks > 1) C += (long)chunk * partStride;

  __shared__ __align__(16) ushort_t At[3 * ABUF];
  __shared__ __align__(16) ushort_t Bt[3 * BBUF];

  int tid = threadIdx.x, wv = tid >> 6, lane = tid & 63;
  int m0 = blockIdx.y * 64, n0 = blockIdx.x * 128;

  int rA = tid >> 2, gA = (tid & 3) ^ ((rA >> 1) & 3);
  const ushort_t* aSrc = A + (size_t)min(m0 + rA, M - 1) * lda + gA * 8 + kbeg;
  int aOff = tid * 8;
  int SB0 = tid, SB1 = tid + 256;
  int rB0 = SB0 >> 2, gB0 = (SB0 & 3) ^ ((rB0 >> 1) & 3);
  int rB1 = SB1 >> 2, gB1 = (SB1 & 3) ^ ((rB1 >> 1) & 3);
  const ushort_t* bSrc0 = W + (size_t)(n0 + rB0) * ldw + gB0 * 8 + kbeg;
  const ushort_t* bSrc1 = W + (size_t)(n0 + rB1) * ldw + gB1 * 8 + kbeg;
  int bOff0 = SB0 * 8, bOff1 = SB1 * 8;

  int wr = wv >> 1, wc = wv & 1;
  int rl = lane & 15, gl = lane >> 4;
  int offA[2], offB[4];
#pragma unroll
  for (int i = 0; i < 2; ++i) {
    int ra = wr * 32 + i * 16 + rl;
    offA[i] = ra * 32 + ((gl ^ ((ra >> 1) & 3)) * 8);
  }
#pragma unroll
  for (int j = 0; j < 4; ++j) {
    int rb = wc * 64 + j * 16 + rl;
    offB[j] = rb * 32 + ((gl ^ ((rb >> 1) & 3)) * 8);
  }

  f32x4 acc[2][4] = {};
  int nk = kChunk >> 5;
  gll16(aSrc, At + aOff);
  gll16(bSrc0, Bt + bOff0);
  gll16(bSrc1, Bt + bOff1);
  if (nk > 1) {
    gll16(aSrc + 32, At + ABUF + aOff);
    gll16(bSrc0 + 32, Bt + BBUF + bOff0);
    gll16(bSrc1 + 32, Bt + BBUF + bOff1);
  }
  int bufT = 0;
  for (int t = 0; t < nk; ++t) {
    int bufN = bufT + 2; if (bufN >= 3) bufN -= 3;
    if (t + 2 < nk) {
      int ko = (t + 2) << 5;
      gll16(aSrc + ko, At + bufN * ABUF + aOff);
      gll16(bSrc0 + ko, Bt + bufN * BBUF + bOff0);
      gll16(bSrc1 + ko, Bt + bufN * BBUF + bOff1);
      asm volatile("s_waitcnt vmcnt(6)" ::: "memory");
    } else if (t + 1 < nk) {
      asm volatile("s_waitcnt vmcnt(3)" ::: "memory");
    } else {
      asm volatile("s_waitcnt vmcnt(0)" ::: "memory");
    }
    __builtin_amdgcn_s_barrier();
    __builtin_amdgcn_sched_barrier(0);
    const ushort_t* Ab = At + bufT * ABUF;
    const ushort_t* Bb = Bt + bufT * BBUF;
    bf16x8 af[2], bw[4];
#pragma unroll
    for (int i = 0; i < 2; ++i) af[i] = *(const bf16x8*)(Ab + offA[i]);
#pragma unroll
    for (int j = 0; j < 4; ++j) bw[j] = *(const bf16x8*)(Bb + offB[j]);
#pragma unroll
    for (int i = 0; i < 2; ++i)
#pragma unroll
      for (int j = 0; j < 4; ++j)
        acc[i][j] = __builtin_amdgcn_mfma_f32_16x16x32_bf16(af[i], bw[j], acc[i][j], 0, 0, 0);
    asm volatile("s_waitcnt lgkmcnt(0)" ::: "memory");
    __builtin_amdgcn_s_barrier();
    __builtin_amdgcn_sched_barrier(0);
    bufT += 1; if (bufT == 3) bufT = 0;
  }

#pragma unroll
  for (int i = 0; i < 2; ++i) {
    int row0 = m0 + wr * 32 + i * 16 + gl * 4;
#pragma unroll
    for (int q = 0; q < 4; ++q) {
      int row = row0 + q;
      if (row >= M) continue;
#pragma unroll
      for (int j = 0; j < 4; ++j) {
        int col = n0 + wc * 64 + j * 16 + rl;
        float v = acc[i][j][q];
        if (bias) v += bias[col];
        if (epi & 1) v = (v > 20.f) ? v : log1pf(__expf(v));
        if (epi & 2) ((ushort_t*)C)[(size_t)row * ldc + col] = f2bf(v);
        else C[(size_t)row * ldc + col] = v;
      }
    }
  }
}

// ===================== single merged weight cast (all regions) =====================
// unit u -> 8 ushorts.  Regions: WIN | WOUT | WX(pad) | wPv | wPa
__global__ __launch_bounds__(256) void castall_k(
    const float* __restrict__ in_w, const float* __restrict__ out_w,
    const float* __restrict__ xw0, const float* __restrict__ xwb0,
    const float* __restrict__ pvw, const float* __restrict__ paw,
    ushort_t* __restrict__ WALL, ushort_t* __restrict__ wPv, ushort_t* __restrict__ wPa)
{
  int u = blockIdx.x * 256 + threadIdx.x;
  if (u >= U_ALL) return;
  const float* src = nullptr;
  ushort_t* dst;
  if (u < U_WIN) { src = in_w + (size_t)u * 8; dst = WALL + (size_t)u * 8; }
  else {
    int u2 = u - U_WIN;
    if (u2 < U_WOUT) { src = out_w + (size_t)u2 * 8; dst = WALL + WIN_SZ + (size_t)u2 * 8; }
    else {
      u2 -= U_WOUT;
      if (u2 < U_WX) {
        int ld = u2 / 24576;
        int j = (u2 - ld * 24576) * 8;
        int l = ld >> 1;
        const float* xs = ((ld & 1) ? xwb0 : xw0) + (size_t)l * 122880;
        int r = j / 1536, k = j - r * 1536;
        if (r < 80) src = xs + r * 1536 + k;
        dst = WALL + WIN_SZ + WOUT_SZ + (size_t)ld * 196608 + j;
      } else {
        u2 -= U_WX;
        if (u2 < U_WPV) { src = pvw + (size_t)u2 * 8; dst = wPv + (size_t)u2 * 8; }
        else { u2 -= U_WPV; src = paw + (size_t)u2 * 8; dst = wPa + (size_t)u2 * 8; }
      }
    }
  }
  f32x4 v0 = {0.f,0.f,0.f,0.f}, v1 = {0.f,0.f,0.f,0.f};
  if (src) { v0 = *(const f32x4*)src; v1 = *(const f32x4*)(src + 4); }
  us8 o = { f2bf(v0[0]), f2bf(v0[1]), f2bf(v0[2]), f2bf(v0[3]),
            f2bf(v1[0]), f2bf(v1[1]), f2bf(v1[2]), f2bf(v1[3]) };
  *(us8*)dst = o;
}

// ===================== fallback casts (small-ws path only) =====================
__global__ __launch_bounds__(256) void cast4_k(const float* __restrict__ s, ushort_t* __restrict__ d, int n4)
{
  int i = blockIdx.x * 256 + threadIdx.x;
  if (i >= n4) return;
  f32x4 v = *(const f32x4*)(s + i * 4);
  us4 o = { f2bf(v[0]), f2bf(v[1]), f2bf(v[2]), f2bf(v[3]) };
  *(us4*)(d + i * 4) = o;
}

__global__ __launch_bounds__(256) void cast8_k(const float* __restrict__ s, ushort_t* __restrict__ d, int n8)
{
  int i = blockIdx.x * 256 + threadIdx.x;
  if (i >= n8) return;
  f32x4 v0 = *(const f32x4*)(s + i * 8);
  f32x4 v1 = *(const f32x4*)(s + i * 8 + 4);
  us8 o = { f2bf(v0[0]), f2bf(v0[1]), f2bf(v0[2]), f2bf(v0[3]),
            f2bf(v1[0]), f2bf(v1[1]), f2bf(v1[2]), f2bf(v1[3]) };
  *(us8*)(d + i * 8) = o;
}

__global__ __launch_bounds__(256) void castx8_k(
    const float* __restrict__ xw0, const float* __restrict__ xwb0,
    ushort_t* __restrict__ WX, int nl)
{
  int i = blockIdx.x * 256 + threadIdx.x;
  if (i >= nl * 2 * 24576) return;
  int ld = i / 24576;
  int j = (i - ld * 24576) * 8;
  int l = ld >> 1;
  const float* xs = ((ld & 1) ? xwb0 : xw0) + (size_t)l * 122880;
  int r = j / 1536, k = j - r * 1536;
  f32x4 v0 = {0.f,0.f,0.f,0.f}, v1 = {0.f,0.f,0.f,0.f};
  if (r < 80) { v0 = *(const f32x4*)(xs + r * 1536 + k); v1 = *(const f32x4*)(xs + r * 1536 + k + 4); }
  us8 o = { f2bf(v0[0]), f2bf(v0[1]), f2bf(v0[2]), f2bf(v0[3]),
            f2bf(v1[0]), f2bf(v1[1]), f2bf(v1[2]), f2bf(v1[3]) };
  *(us8*)(WX + (size_t)ld * 196608 + j) = o;
}

// ===================== merged im2col (video + audio) =====================
__global__ __launch_bounds__(256) void im2col_va(
    const float* __restrict__ xv, ushort_t* __restrict__ Av,
    const float* __restrict__ xa, ushort_t* __restrict__ Aa)
{
  int i = blockIdx.x * 256 + threadIdx.x;
  if (i < 1568 * 768) {
    int m = i / 768, k = i % 768;
    int c = k >> 8, r = k & 255;
    int kh = r >> 4, kw = r & 15;
    int bt = m / 196, n = m % 196;
    int b = bt / TT, t = bt % TT;
    int hb = n / 14, wb = n % 14;
    Av[i] = f2bf(xv[(size_t)b * 602112 + (size_t)c * 200704 + t * 50176 + (hb * 16 + kh) * 224 + wb * 16 + kw]);
    return;
  }
  i -= 1568 * 768;
  if (i >= 192 * 256) return;
  int m = i / 256, k = i % 256;
  int kh = k >> 4, kw = k & 15;
  int b = m / 96, q = m % 96;
  int tb = q >> 2, fb = q & 3;
  Aa[i] = f2bf(xa[(size_t)b * 24576 + (fb * 16 + kw) * 384 + tb * 16 + kh]);
}

// ===================== assemble tokens + gather =====================
__global__ __launch_bounds__(256) void assemble_k(
    const float* __restrict__ tokv, const float* __restrict__ toka,
    const float* __restrict__ pos_v, const float* __restrict__ pos_a,
    const float* __restrict__ tpos_v, const float* __restrict__ tpos_a,
    const float* __restrict__ cls_v, const float* __restrict__ cls_a,
    const float* __restrict__ glob_v, const float* __restrict__ glob_a,
    const int* __restrict__ vis_idx,
    float* __restrict__ h, float* __restrict__ res)
{
  int i = blockIdx.x * 256 + threadIdx.x;
  if (i >= NROWS * DD) return;
  int d = i % DD;
  int bl = i / DD;
  int r = bl % LV, b = bl / LV;
  int tok = vis_idx[b * LV + r];
  int t = tok / 224, q = tok % 224;
  float v;
  if (q == 0) v = cls_v[d];
  else if (q <= 196) {
    int n = q - 1;
    v = tokv[((size_t)(b * TT + t) * 196 + n) * DD + d] + pos_v[n * DD + d] + tpos_v[t * DD + d];
  } else if (q == 197) v = glob_v[d];
  else if (q == 198) v = cls_a[d];
  else if (q <= 222) {
    int n = q - 199;
    v = toka[((size_t)b * 96 + t * 24 + n) * DD + d] + pos_a[n * DD + d] + tpos_a[t * DD + d];
  } else v = glob_a[d];
  h[i] = v;
  res[i] = 0.f;
}

// ============ fused (out-proj split-K reduce OR h read) + residual + RMSNorm ============
__global__ __launch_bounds__(256) void rmsnorm_k(
    const float* __restrict__ hsrc, const float* __restrict__ part,
    float* __restrict__ res, ushort_t* __restrict__ hn, const float* __restrict__ nw)
{
  int row = blockIdx.x;
  float* rp = res + (size_t)row * DD;
  ushort_t* op = hn + (size_t)row * DD;
  int tid = threadIdx.x;
  float v[3];
  float ss = 0.f;
#pragma unroll
  for (int i = 0; i < 3; ++i) {
    int c = tid + i * 256;
    float x;
    if (part) {
      x = part[(size_t)row * DD + c] + part[688128 + (size_t)row * DD + c]
        + part[2 * 688128 + (size_t)row * DD + c] + part[3 * 688128 + (size_t)row * DD + c];
    } else {
      x = hsrc[(size_t)row * DD + c];
    }
    x += rp[c];
    v[i] = x;
    ss += x * x;
  }
  for (int m = 1; m < 64; m <<= 1) ss += __shfl_xor(ss, m, 64);
  __shared__ float sred[4];
  if ((tid & 63) == 0) sred[tid >> 6] = ss;
  __syncthreads();
  float tot = sred[0] + sred[1] + sred[2] + sred[3];
  float sc = rsqrtf(tot / (float)DD + 1e-5f);
#pragma unroll
  for (int i = 0; i < 3; ++i) {
    int c = tid + i * 256;
    rp[c] = v[i];
    op[c] = f2bf(v[i] * sc * nw[c]);
  }
}

// ======== causal depthwise conv (k=4, bf16 in) + silu -> bf16, 4 channels/thread ========
__global__ __launch_bounds__(256) void conv_k(
    const ushort_t* __restrict__ xz,
    const float* __restrict__ cw, const float* __restrict__ cb,
    const float* __restrict__ cwb, const float* __restrict__ cbb,
    ushort_t* __restrict__ xcFb, ushort_t* __restrict__ xcBb)
{
  int i = blockIdx.x * 256 + threadIdx.x;
  if (i >= NROWS * (DI_ / 4)) return;
  int dv = (i % (DI_ / 4)) * 4;
  int bl = i / (DI_ / 4);
  int l = bl % LV, b = bl / LV;
  const ushort_t* xzb = xz + (size_t)b * LV * (2 * DI_);
  f32x4 accf = *(const f32x4*)(cb + dv);
  f32x4 accb = *(const f32x4*)(cbb + dv);
  f32x4 tf[4], tb[4];
#pragma unroll
  for (int e = 0; e < 4; ++e) {
    tf[e] = *(const f32x4*)(cw + (dv + e) * 4);
    tb[e] = *(const f32x4*)(cwb + (dv + e) * 4);
  }
#pragma unroll
  for (int j = 0; j < 4; ++j) {
    int lp = l - 3 + j;
    if (lp >= 0) {
      us4 xf = *(const us4*)(xzb + (size_t)lp * (2 * DI_) + dv);
      us4 xb = *(const us4*)(xzb + (size_t)(LV - 1 - lp) * (2 * DI_) + dv);
#pragma unroll
      for (int e = 0; e < 4; ++e) {
        accf[e] += bf2f(xf[e]) * tf[e][j];
        accb[e] += bf2f(xb[e]) * tb[e][j];
      }
    }
  }
  us4 of, ob;
#pragma unroll
  for (int e = 0; e < 4; ++e) {
    of[e] = f2bf(silu_f(accf[e]));
    ob[e] = f2bf(silu_f(accb[e]));
  }
  *(us4*)(xcFb + (size_t)bl * DI_ + dv) = of;
  *(us4*)(xcBb + (size_t)bl * DI_ + dv) = ob;
}

// ======== fused split-K reduce + dt "GEMM" (K=48) + softplus -> bf16 dt ========
__global__ __launch_bounds__(256) void reddt_k(
    const float* __restrict__ pF, const float* __restrict__ pB,
    float* __restrict__ prF, float* __restrict__ prB,
    const float* __restrict__ dwF, const float* __restrict__ dwB,
    const float* __restrict__ dbF, const float* __restrict__ dbB,
    ushort_t* __restrict__ dtFb, ushort_t* __restrict__ dtBb)
{
  int dir = blockIdx.y;
  const float* part = dir ? pB : pF;
  float* proj = dir ? prB : prF;
  const float* dw = dir ? dwB : dwF;
  const float* db = dir ? dbB : dbF;
  ushort_t* dt = dir ? dtBb : dtFb;
  int r0 = blockIdx.x * 8;
  int tid = threadIdx.x;
  __shared__ float sdtr[8][48];
  for (int o = tid; o < 8 * 80; o += 256) {
    int r = o / 80, col = o - (o / 80) * 80;
    int row = r0 + r;
    float s = 0.f;
#pragma unroll
    for (int c = 0; c < 8; ++c) s += part[c * (NROWS * 128) + row * 128 + col];
    proj[row * 80 + col] = s;
    if (col < 48) sdtr[r][col] = s;
  }
  __syncthreads();
#pragma unroll
  for (int q = 0; q < 6; ++q) {
    int d = q * 256 + tid;
    f32x4 w[12];
#pragma unroll
    for (int e = 0; e < 12; ++e) w[e] = *(const f32x4*)(dw + (size_t)d * 48 + e * 4);
    float bias = db[d];
#pragma unroll
    for (int r = 0; r < 8; ++r) {
      float s = bias;
#pragma unroll
      for (int e = 0; e < 12; ++e) {
#pragma unroll
        for (int u = 0; u < 4; ++u) s += sdtr[r][e * 4 + u] * w[e][u];
      }
      s = (s > 20.f) ? s : log1pf(__expf(s));
      dt[(size_t)(r0 + r) * DI_ + d] = f2bf(s);
    }
  }
}

// ===================== chunked selective scan (dt precomputed, bf16) ===========
__global__ __launch_bounds__(256) void scanA_k(
    const ushort_t* __restrict__ xcFb, const ushort_t* __restrict__ dtF, const float* __restrict__ prF,
    const ushort_t* __restrict__ xcBb, const ushort_t* __restrict__ dtB, const float* __restrict__ prB,
    const float* __restrict__ AlF, const float* __restrict__ AlB,
    float* __restrict__ hloc, float* __restrict__ Pb)
{
  int dir = blockIdx.z;
  const ushort_t* xc = dir ? xcBb : xcFb;
  const ushort_t* dt = dir ? dtB : dtF;
  const float* pr = dir ? prB : prF;
  const float* Al = dir ? AlB : AlF;
  int c = blockIdx.y;
  int g = blockIdx.x * 16 + (threadIdx.x >> 4);
  int n = threadIdx.x & 15;
  int b = g / DI_, d = g % DI_;
  float An = -__expf(Al[d * NS_ + n]);
  const ushort_t* xcp = xc + (size_t)b * LV * DI_ + d;
  const ushort_t* dtp = dt + (size_t)b * LV * DI_ + d;
  const float* prp = pr + (size_t)b * LV * 80;
  int l0 = c * CLEN;
  float hs = 0.f, S = 0.f;
  float dtv = bf2f(dtp[(size_t)l0 * DI_]);
  float xcv = bf2f(xcp[(size_t)l0 * DI_]);
  float bn  = prp[l0 * 80 + 48 + n];
  for (int kk = 0; kk < CLEN; ++kk) {
    float dtv_n = 0.f, xcv_n = 0.f, bn_n = 0.f;
    if (kk < CLEN - 1) {
      int l1 = l0 + kk + 1;
      dtv_n = bf2f(dtp[(size_t)l1 * DI_]);
      xcv_n = bf2f(xcp[(size_t)l1 * DI_]);
      bn_n  = prp[l1 * 80 + 48 + n];
    }
    hs = __expf(dtv * An) * hs + dtv * bn * xcv;
    S += dtv;
    dtv = dtv_n; xcv = xcv_n; bn = bn_n;
  }
  int idx = ((dir * 3072 + g) * 6 + c) * NS_ + n;
  hloc[idx] = hs;
  Pb[idx] = __expf(An * S);
}

// pass BC: both dirs in parallel warps; in-block h_start prefix; fused combine.
__global__ __launch_bounds__(256) void scanBC_k(
    const ushort_t* __restrict__ xcFb, const ushort_t* __restrict__ dtF, const float* __restrict__ prF,
    const ushort_t* __restrict__ xcBb, const ushort_t* __restrict__ dtB, const float* __restrict__ prB,
    const float* __restrict__ AlF, const float* __restrict__ AlB,
    const float* __restrict__ DpF, const float* __restrict__ DpB,
    const float* __restrict__ hloc, const float* __restrict__ Pb,
    const ushort_t* __restrict__ xz, ushort_t* __restrict__ yc)
{
  int c = blockIdx.y;                 // fwd chunk index
  int tid = threadIdx.x;
  int n = tid & 15, gi = (tid >> 4) & 7, dir = tid >> 7;
  int g = blockIdx.x * 8 + gi;
  int b = g / DI_, d = g % DI_;
  __shared__ float sbuf[2][8][65];

  const ushort_t* xc = dir ? xcBb : xcFb;
  const ushort_t* dt = dir ? dtB : dtF;
  const float* pr = dir ? prB : prF;
  const float* Al = dir ? AlB : AlF;
  const float* Dpp = dir ? DpB : DpF;
  int myc = dir ? (6 - c) : c;
  float An = -__expf(Al[d * NS_ + n]);
  float Dpd = Dpp[d];
  float hs = 0.f;
  for (int j = 0; j < myc; ++j) {
    int idx = ((dir * 3072 + g) * 6 + j) * NS_ + n;
    hs = Pb[idx] * hs + hloc[idx];
  }
  const ushort_t* xcp = xc + (size_t)b * LV * DI_ + d;
  const ushort_t* dtp = dt + (size_t)b * LV * DI_ + d;
  const float* prp = pr + (size_t)b * LV * 80;
  int l0 = myc * CLEN;
  float dtv = bf2f(dtp[(size_t)l0 * DI_]);
  float xcv = bf2f(xcp[(size_t)l0 * DI_]);
  float bn  = prp[l0 * 80 + 48 + n];
  float cn  = prp[l0 * 80 + 64 + n];
  for (int kk = 0; kk < CLEN; ++kk) {
    float dtv_n = 0.f, xcv_n = 0.f, bn_n = 0.f, cn_n = 0.f;
    if (kk < CLEN - 1) {
      int l1 = l0 + kk + 1;
      dtv_n = bf2f(dtp[(size_t)l1 * DI_]);
      xcv_n = bf2f(xcp[(size_t)l1 * DI_]);
      bn_n  = prp[l1 * 80 + 48 + n];
      cn_n  = prp[l1 * 80 + 64 + n];
    }
    hs = __expf(dtv * An) * hs + dtv * bn * xcv;
    float p = hs * cn;
    p += __shfl_xor(p, 1, 16);
    p += __shfl_xor(p, 2, 16);
    p += __shfl_xor(p, 4, 16);
    p += __shfl_xor(p, 8, 16);
    if (n == 0) {
      int off = dir ? (CLEN - 1 - kk) : kk;
      sbuf[dir][gi][off] = p + xcv * Dpd;
    }
    dtv = dtv_n; xcv = xcv_n; bn = bn_n; cn = cn_n;
  }
  __syncthreads();
  for (int oid = tid; oid < 512; oid += 256) {
    int gi2 = oid & 7, kk = oid >> 3;
    int g2 = blockIdx.x * 8 + gi2;
    int b2 = g2 / DI_, d2 = g2 % DI_;
    int l = c * CLEN + kk;
    float z = bf2f(xz[((size_t)b2 * LV + l) * 3072 + 1536 + d2]);
    float v = (sbuf[0][gi2][kk] + sbuf[1][gi2][kk]) * silu_f(z);
    yc[((size_t)b2 * LV + l) * DI_ + d2] = f2bf(v);
  }
}

// ===================== final: out = res + sum(partO) ==============
__global__ __launch_bounds__(256) void final_k(
    const float* __restrict__ res, const float* __restrict__ part, float* __restrict__ out)
{
  int i = blockIdx.x * 256 + threadIdx.x;
  if (i >= NROWS * DD) return;
  out[i] = res[i] + part[i] + part[688128 + i] + part[2 * 688128 + i] + part[3 * 688128 + i];
}

extern "C" void kernel_launch(void* const* d_in, const int* in_sizes, int n_in,
                              void* d_out, int out_size, void* d_ws, size_t ws_size,
                              hipStream_t stream)
{
  const float* x_v = (const float*)d_in[0];
  const float* x_a = (const float*)d_in[1];
  const float* patch_v_w = (const float*)d_in[2];
  const float* patch_v_b = (const float*)d_in[3];
  const float* patch_a_w = (const float*)d_in[4];
  const float* patch_a_b = (const float*)d_in[5];
  const float* pos_v = (const float*)d_in[6];
  const float* pos_a = (const float*)d_in[7];
  const float* tpos_v = (const float*)d_in[8];
  const float* tpos_a = (const float*)d_in[9];
  const float* cls_v = (const float*)d_in[10];
  const float* cls_a = (const float*)d_in[11];
  const float* glob_v = (const float*)d_in[12];
  const float* glob_a = (const float*)d_in[13];
  const float* norm_w = (const float*)d_in[14];
  const float* in_w = (const float*)d_in[15];
  const float* conv_w = (const float*)d_in[16];
  const float* conv_b = (const float*)d_in[17];
  const float* conv_w_b = (const float*)d_in[18];
  const float* conv_b_b = (const float*)d_in[19];
  const float* xproj_w = (const float*)d_in[20];
  const float* xproj_w_b = (const float*)d_in[21];
  const float *dt_w, *dt_bias, *dt_w_b, *dt_bias_b;
  if (in_sizes[23] == DEPTH_ * DI_ * RK_) {  // dict order: dt_w, dt_w_b, dt_b, dt_b_b
    dt_w = (const float*)d_in[22]; dt_w_b = (const float*)d_in[23];
    dt_bias = (const float*)d_in[24]; dt_bias_b = (const float*)d_in[25];
  } else {                                   // signature order
    dt_w = (const float*)d_in[22]; dt_bias = (const float*)d_in[23];
    dt_w_b = (const float*)d_in[24]; dt_bias_b = (const float*)d_in[25];
  }
  const float* A_log = (const float*)d_in[26];
  const float* A_log_b = (const float*)d_in[27];
  const float* D_par = (const float*)d_in[28];
  const float* D_par_b = (const float*)d_in[29];
  const float* out_w = (const float*)d_in[30];
  const int* vis_idx = (const int*)d_in[31];

  // ---------------- workspace layout (float units) ----------------
  float* ws = (float*)d_ws;
  float* res   = ws;                 // 688128
  float* hbuf  = ws + 688128;        // 688128 (phase-1 h only)
  float* R1    = ws + 1376256;       // 2752512: phase1 | xproj partials | hloc+Pb | outproj partials
  float* R2f   = ws + 4128768;       // 688128: hn_bf | ycb
  float* R3    = ws + 4816896;       // 1376256: xcFb + xcBb (bf16)
  float* xz    = ws + 7569408;       // 896*3072 bf16 (phase1: Av_bf alias)
  float* dtFf  = ws + 10321920;      // 896*1536 bf16
  float* dtBf  = ws + 11698176;      // 896*1536 bf16
  float* projF = ws + 13074432;      // 71680
  float* projB = ws + 13146112;      // 71680
  float* wPvf  = ws + 13217792;      // 294912 (589824 bf16)
  float* WALLf = ws + 13512704;      // WALL_USH ushorts

  // R1 views
  float* partF = R1;                         // 8*896*128 = 917504
  float* partB = R1 + 917504;
  float* hloc  = R1;                         // 589824
  float* Pb    = R1 + 589824;                // 589824
  float* partO = R1;                         // 4*688128 = 2752512
  // phase-1 views
  float* tokv  = R1;                         // 1568*768
  float* toka  = R1 + 1204224;               // 192*768
  ushort_t* Av_bf = (ushort_t*)xz;           // 1568*768 bf16
  ushort_t* wPv   = (ushort_t*)wPvf;
  ushort_t* wPa   = (ushort_t*)dtFf;         // 768*256 bf16 (dead in phase 1)
  ushort_t* Aa_bf = ((ushort_t*)dtFf) + 196608;
  // R2 views
  ushort_t* hn_bf = (ushort_t*)R2f;          // 896*768
  ushort_t* ycb   = (ushort_t*)R2f;          // 896*1536
  // R3 views
  ushort_t* xcFb = (ushort_t*)R3;            // 896*1536
  ushort_t* xcBb = ((ushort_t*)R3) + 1376256;
  ushort_t* xzb  = (ushort_t*)xz;            // 896*3072 bf16
  ushort_t* dtFb = (ushort_t*)dtFf;
  ushort_t* dtBb = (ushort_t*)dtBf;

  size_t need_big = ((size_t)13512704 + (WALL_USH + 1) / 2) * 4;
  int bigws = ws_size >= need_big;
  ushort_t* WALL = (ushort_t*)WALLf;
  ushort_t* WIN  = WALL;
  ushort_t* WOUT = WIN + WIN_SZ;
  ushort_t* WX   = WOUT + WOUT_SZ;

  dim3 blk(256);

  // ---- single merged weight cast (all regions, incl. patch weights) ----
  if (bigws) {
    castall_k<<<(U_ALL + 255) / 256, blk, 0, stream>>>(
        in_w, out_w, xproj_w, xproj_w_b, patch_v_w, patch_a_w, WALL, wPv, wPa);
  } else {
    cast4_k<<<576, blk, 0, stream>>>(patch_v_w, wPv, 147456);
    cast4_k<<<192, blk, 0, stream>>>(patch_a_w, wPa, 49152);
  }

  // ---- phase 1: patch embed + assemble ----
  im2col_va<<<4896, blk, 0, stream>>>(x_v, Av_bf, x_a, Aa_bf);
  mfma_gemm<<<dim3(6, 25, 1), blk, 0, stream>>>(Av_bf, nullptr, 768, wPv, nullptr, 768,
                                                patch_v_b, nullptr, tokv, nullptr, 768,
                                                1568, 768, 1, 0, 0);
  mfma_gemm<<<dim3(6, 3, 1), blk, 0, stream>>>(Aa_bf, nullptr, 256, wPa, nullptr, 256,
                                               patch_a_b, nullptr, toka, nullptr, 768,
                                               192, 256, 1, 0, 0);
  assemble_k<<<2688, blk, 0, stream>>>(tokv, toka, pos_v, pos_a, tpos_v, tpos_a,
                                       cls_v, cls_a, glob_v, glob_a, vis_idx, hbuf, res);

  // ---- phase 2: layers 0..14 (layer 15's compute is dead except res += h) ----
  for (int l = 0; l < NRUN; ++l) {
    const float* nw  = norm_w + l * DD;
    const float* cw  = conv_w + l * DI_ * KC_;
    const float* cb  = conv_b + l * DI_;
    const float* cwb = conv_w_b + l * DI_ * KC_;
    const float* cbb = conv_b_b + l * DI_;
    const float* dwF = dt_w + (size_t)l * DI_ * RK_;
    const float* dwB = dt_w_b + (size_t)l * DI_ * RK_;
    const float* dbi = dt_bias + l * DI_;
    const float* dbib = dt_bias_b + l * DI_;
    const float* al  = A_log + (size_t)l * DI_ * NS_;
    const float* alb = A_log_b + (size_t)l * DI_ * NS_;
    const float* dp  = D_par + l * DI_;
    const float* dpb = D_par_b + l * DI_;

    ushort_t *wIn, *wOut, *wXF, *wXB;
    if (bigws) {
      wIn  = WIN + (size_t)l * 2359296;
      wOut = WOUT + (size_t)l * 1179648;
      wXF  = WX + (size_t)(l * 2) * 196608;
      wXB  = wXF + 196608;
    } else {
      wIn = WALL; wOut = wIn + 2359296; wXF = wOut + 1179648; wXB = wXF + 196608;
      cast8_k<<<(2359296 / 8 + 255) / 256, blk, 0, stream>>>(in_w + (size_t)l * 2359296, wIn, 2359296 / 8);
      cast8_k<<<(1179648 / 8 + 255) / 256, blk, 0, stream>>>(out_w + (size_t)l * 1179648, wOut, 1179648 / 8);
      castx8_k<<<(2 * 24576 + 255) / 256, blk, 0, stream>>>(xproj_w + (size_t)l * 122880,
                                                            xproj_w_b + (size_t)l * 122880, wXF, 1);
    }

    // residual add + RMSNorm (fuses previous layer's out-proj split-K reduce)
    rmsnorm_k<<<NROWS, blk, 0, stream>>>(hbuf, l ? partO : nullptr, res, hn_bf, nw);
    // in-proj: [896,3072] = hn @ in_w^T, bf16 out
    mfma_gemm<<<dim3(24, 14, 1), blk, 0, stream>>>(hn_bf, nullptr, 768, wIn, nullptr, 768,
                                                   nullptr, nullptr, (float*)xzb, nullptr, 3072,
                                                   NROWS, 768, 1, 0, 2);
    conv_k<<<1344, blk, 0, stream>>>(xzb, cw, cb, cwb, cbb, xcFb, xcBb);
    // xproj both dirs, split-K x8
    mfma_gemm<<<dim3(1, 14, 16), blk, 0, stream>>>(xcFb, xcBb, 1536, wXF, wXB, 1536,
                                                   nullptr, nullptr, partF, partB, 128,
                                                   NROWS, 1536, 8, NROWS * 128, 0);
    // fused reduce + dt(+softplus) -> bf16
    reddt_k<<<dim3(112, 2, 1), blk, 0, stream>>>(partF, partB, projF, projB,
                                                 dwF, dwB, dbi, dbib, dtFb, dtBb);
    // chunked scan: passA then fused passB+combine
    scanA_k<<<dim3(192, 6, 2), blk, 0, stream>>>(xcFb, dtFb, projF, xcBb, dtBb, projB,
                                                 al, alb, hloc, Pb);
    scanBC_k<<<dim3(384, NCH, 1), blk, 0, stream>>>(xcFb, dtFb, projF, xcBb, dtBb, projB,
                                                    al, alb, dp, dpb, hloc, Pb, xzb, ycb);
    // out-proj split-K x4: partials reduced by next layer's rmsnorm (or final_k)
    mfma_gemm<<<dim3(6, 14, 4), blk, 0, stream>>>(ycb, nullptr, 1536, wOut, nullptr, 1536,
                                                  nullptr, nullptr, partO, nullptr, 768,
                                                  NROWS, 1536, 4, NROWS * DD, 0);
  }

  final_k<<<2688, blk, 0, stream>>>(res, partO, (float*)d_out);
}